// Round 19
// baseline (305.157 us; speedup 1.0000x reference)
//
#include <hip/hip_runtime.h>
#include <stdint.h>

typedef __attribute__((ext_vector_type(8))) short short8;
typedef __attribute__((ext_vector_type(16))) float f32x16;
typedef __attribute__((ext_vector_type(4))) unsigned short ushort4v;

union S8 { short8 v; unsigned short u[8]; };

static __device__ __forceinline__ unsigned short f2bf(float f) {
  union { float f; unsigned u; } v; v.f = f;
  unsigned r = v.u + 0x7fffu + ((v.u >> 16) & 1u);
  return (unsigned short)(r >> 16);
}
static __device__ __forceinline__ float bf2f(unsigned short u) {
  union { unsigned u; float f; } v; v.u = ((unsigned)u) << 16;
  return v.f;
}

static __device__ __forceinline__ void glds16(const void* g, void* l) {
  __builtin_amdgcn_global_load_lds(
      (const __attribute__((address_space(1))) unsigned int*)g,
      (__attribute__((address_space(3))) unsigned int*)l, 16, 0, 0);
}

// ---------------- prep: W -> per-(g8,kt) 16KB B-fragment images ----------------
__global__ __launch_bounds__(256) void prep_w(const float* __restrict__ Wa,
                                              const float* __restrict__ Wb,
                                              const float* __restrict__ Wc,
                                              unsigned short* __restrict__ wfrag) {
  int t    = blockIdx.x * 256 + threadIdx.x;
  int lane = t & 63;
  int tt   = (t >> 6) & 7;
  int ks   = (t >> 9) & 1;
  int kt   = (t >> 10) & 31;
  int g8   = (t >> 15) & 7;
  int c    = t >> 18;
  const float* W = (c == 0) ? Wa : (c == 1) ? Wb : Wc;
  int s  = tt >> 2, gt = tt & 3;
  int g  = g8*128 + gt*32 + (lane & 31);
  int k0 = kt*32 + ks*16 + ((lane >> 5) * 8);
  const float* src = W + (size_t)s * 1048576 + (size_t)k0 * 1024 + g;
  unsigned short* dst = wfrag + (size_t)t * 8;
#pragma unroll
  for (int e = 0; e < 8; ++e) dst[e] = f2bf(src[(size_t)e * 1024]);
}

// ---------------- prep: x -> ALL THREE per-view A-fragment images ----------------
__global__ __launch_bounds__(256) void prep_x_all(const float* __restrict__ x,
                                                  unsigned short* __restrict__ ximg) {
  __shared__ unsigned short sx[33024];   // 32 rows x 1032 (pad 8)
  int vid = blockIdx.x;
  const float* src = x + (size_t)vid * 32768;
  int tid = threadIdx.x;
  for (int j = tid; j < 8192; j += 256) {
    float4 u = *(const float4*)(src + (size_t)j * 4);
    int i = j >> 8;
    int r = (j & 255) * 4;
    unsigned short* d = &sx[i*1032 + r];
    d[0] = f2bf(u.x); d[1] = f2bf(u.y); d[2] = f2bf(u.z); d[3] = f2bf(u.w);
  }
  __syncthreads();
  int lane = tid & 63;
  int ks   = (tid >> 6) & 1;
  int half = tid >> 7;
  int i0 = lane & 31;
  int kq = (lane >> 5) * 8;
#pragma unroll 1
  for (int kth = 0; kth < 16; ++kth) {
    int kt = half*16 + kth;
    int k0 = kt*32 + ks*16 + kq;
    int b = k0 >> 5, cz = k0 & 31;
    size_t t8 = ((((size_t)vid*32 + kt)*2 + ks)*64 + lane) * 8;
    {
      S8 pk;
#pragma unroll
      for (int e = 0; e < 8; ++e) pk.u[e] = sx[b*1032 + (cz + e)*32 + i0];
      *(short8*)(ximg + t8) = pk.v;
    }
    {
      short8 v = *(const short8*)&sx[i0*1032 + k0];
      *(short8*)(ximg + 16777216 + t8) = v;
    }
    {
      short8 v = *(const short8*)&sx[b*1032 + i0*32 + cz];
      *(short8*)(ximg + 33554432 + t8) = v;
    }
  }
}

// ---------------- prep: x -> per-VIEW A-fragment image, single channel (fallback) ----------------
__global__ __launch_bounds__(256) void prep_x2(const float* __restrict__ x,
                                               int c, unsigned short* __restrict__ ximg) {
  int t = blockIdx.x * 256 + threadIdx.x;
  int lane = t & 63;
  int ks = (t >> 6) & 1;
  int kt = (t >> 7) & 31;
  int vid = t >> 12;
  const float* src = x + (size_t)vid * 32768;
  int i = lane & 31;
  int k0 = kt*32 + ks*16 + ((lane >> 5) * 8);
  S8 pk;
  if (c == 0) {
#pragma unroll
    for (int e = 0; e < 8; ++e) pk.u[e] = f2bf(src[(size_t)(k0 + e)*32 + i]);
  } else {
    const float* sp = (c == 1) ? (src + i*1024 + k0)
                               : (src + (k0 >> 5)*1024 + i*32 + (k0 & 31));
    float4 u0 = *(const float4*)sp, u1 = *(const float4*)(sp + 4);
    pk.u[0]=f2bf(u0.x); pk.u[1]=f2bf(u0.y); pk.u[2]=f2bf(u0.z); pk.u[3]=f2bf(u0.w);
    pk.u[4]=f2bf(u1.x); pk.u[5]=f2bf(u1.y); pk.u[6]=f2bf(u1.z); pk.u[7]=f2bf(u1.w);
  }
  *(short8*)(ximg + (size_t)t * 8) = pk.v;
}

// ---------------- prep: softmax A, Aoff frags, diag, BN affine ----------------
__global__ __launch_bounds__(256) void prep_misc(
    const float* e0, const int* a0, const float* b0, const float* g0, const float* be0, const float* rm0, const float* rv0,
    const float* e1, const int* a1, const float* b1, const float* g1, const float* be1, const float* rm1, const float* rv1,
    const float* e2, const int* a2, const float* b2, const float* g2, const float* be2, const float* rm2, const float* rv2,
    unsigned short* __restrict__ aofrag, float* __restrict__ diagA,
    float* __restrict__ scale2, float* __restrict__ shift2) {
  __shared__ float A[64][64];
  int c = blockIdx.x;
  int tid = threadIdx.x;
  const float* ev = (c==0)?e0:(c==1)?e1:e2;
  const int*   ad = (c==0)?a0:(c==1)?a1:a2;
  const float* bb = (c==0)?b0:(c==1)?b1:b2;
  const float* gm = (c==0)?g0:(c==1)?g1:g2;
  const float* bt = (c==0)?be0:(c==1)?be1:be2;
  const float* rm = (c==0)?rm0:(c==1)?rm1:rm2;
  const float* rv = (c==0)?rv0:(c==1)?rv1:rv2;
  if (tid < 64) {
    int n = tid;
    float mx = -3.0e38f;
    for (int m = 0; m < 64; ++m) {
      float lg = (ad[n*64+m] > 0) ? ev[n*64+m] : -9.0e15f;
      A[n][m] = lg; mx = fmaxf(mx, lg);
    }
    float ssum = 0.f;
    for (int m = 0; m < 64; ++m) { float p = __expf(A[n][m] - mx); A[n][m] = p; ssum += p; }
    float inv = 1.f / ssum;
    for (int m = 0; m < 64; ++m) A[n][m] *= inv;
  }
  __syncthreads();
  if (tid < 64) diagA[c*64 + tid] = A[tid][tid];
  for (int idx = tid; idx < 4096; idx += 256) {
    int e  = idx & 7;
    int l  = (idx >> 3) & 63;
    int ks = (idx >> 9) & 3;
    int nt = idx >> 11;
    int n = nt*32 + (l & 31);
    int m = ks*16 + ((l >> 5) * 8) + e;
    float vv = (m == n) ? 0.f : A[n][m];
    aofrag[c*4096 + idx] = f2bf(vv);
  }
  for (int g = tid; g < 1024; g += 256) {
    float sc = gm[g] * rsqrtf(rv[g] + 1e-5f);
    scale2[c*1024 + g] = sc;
    shift2[c*1024 + g] = bt[g] + (bb[g] - rm[g]) * sc;
  }
}

// ---------------- fallback A loader (IMG=0 only): f32 direct gather ----------------
template<int CH>
__device__ __forceinline__ void loadAfb(float av[2][8], const float* __restrict__ sview,
                                        int d0, int lh, int kt) {
#pragma unroll
  for (int ks = 0; ks < 2; ++ks) {
    int kb = kt*32 + ks*16 + lh*8;
    if (CH == 0) {
#pragma unroll
      for (int e = 0; e < 8; ++e) av[ks][e] = sview[(size_t)(kb + e)*32 + d0];
    } else if (CH == 1) {
      const float* sp = sview + d0*1024 + kb;
      *(float4*)&av[ks][0] = *(const float4*)sp;
      *(float4*)&av[ks][4] = *(const float4*)(sp + 4);
    } else {
      const float* sp = sview + kt*1024 + d0*32 + ks*16 + lh*8;
      *(float4*)&av[ks][0] = *(const float4*)sp;
      *(float4*)&av[ks][4] = *(const float4*)(sp + 4);
    }
  }
}

// ---------------- main fused channel kernel (r15 geometry, barrier-light K-loop) ----------------
// Block = (batch b, g8, gp): 256 rows (8 vids x 32) x 64 cols x 2 s. 2 blocks/CU.
// All-glds staging (uniform 6-glds/kt queue -> counted vmcnt(6) is exact and
// robust: no VGPR-return loads inside the counted window, no spill hazard).
// Per kt: no intra-kt barriers; sole boundary vmcnt(6)+s_barrier.
template<int CH, int IMG>
__global__ __launch_bounds__(256, 2) void gconv(
    const float* __restrict__ x, const int* __restrict__ idxp,
    const unsigned short* __restrict__ wimg, const unsigned short* __restrict__ ximg,
    const unsigned short* __restrict__ aofrag,
    const float* __restrict__ diagA, const float* __restrict__ scale2,
    const float* __restrict__ shift2, float* __restrict__ out) {
  __shared__ alignas(128) char lds[73728];
  int tid = threadIdx.x, lane = tid & 63, wave = tid >> 6;
  int l31 = lane & 31, lh = lane >> 5;
  int wr = wave >> 1, sB = wave & 1;
  int bid = blockIdx.x;
  int g8 = bid & 7, gp = (bid >> 3) & 1, b = bid >> 4;

  const char* wimgG8 = (const char*)wimg + (size_t)g8 * 524288 + lane*16;
  const char* srcAw  = (const char*)ximg + ((size_t)b*8 + 2*wave) * 65536 + lane*16;
  const float* xw0 = x + ((size_t)b*8 + 2*wave) * 32768;       // IMG=0 only
  const float* xw1 = xw0 + 32768;                              // IMG=0 only

  f32x16 acc[4][2];
#pragma unroll
  for (int mt = 0; mt < 4; ++mt)
#pragma unroll
    for (int g2 = 0; g2 < 2; ++g2)
#pragma unroll
      for (int r = 0; r < 16; ++r) acc[mt][g2][r] = 0.f;

  char* p0 = lds; char* p1 = lds + 24576; char* p2 = lds + 49152;

  auto stageA = [&](char* dst, int t) {     // 4 glds: vids 2w,2w+1 x ks 0,1
    if (IMG) {
#pragma unroll
      for (int j = 0; j < 4; ++j) {
        const char* s = srcAw + (size_t)(j >> 1)*65536 + (size_t)t*2048 + (j & 1)*1024;
        glds16(s, dst + (2*wave + (j >> 1))*2048 + (j & 1)*1024);
      }
    } else {
#pragma unroll
      for (int j = 0; j < 2; ++j) {
        alignas(16) float av[2][8];
        loadAfb<CH>(av, j ? xw1 : xw0, l31, lh, t);
#pragma unroll
        for (int ks = 0; ks < 2; ++ks) {
          S8 pk;
#pragma unroll
          for (int e = 0; e < 8; ++e) pk.u[e] = f2bf(av[ks][e]);
          *(short8*)(dst + (2*wave + j)*2048 + ks*1024 + lane*16) = pk.v;
        }
      }
    }
  };
  auto stageB = [&](char* dst, int t) {     // 2 glds: (ks=w>>1, s=w&1, g2=jj)
#pragma unroll
    for (int jj = 0; jj < 2; ++jj) {
      const char* s = wimgG8 + (size_t)(((t*2 + (wave >> 1))*8) + (wave & 1)*4 + gp*2 + jj)*1024;
      glds16(s, dst + 16384 + (wave*2 + jj)*1024);
    }
  };

  // ---- prologue: stage t0, t1 ----
  stageA(p0, 0); stageB(p0, 0);
  stageA(p1, 1); stageB(p1, 1);
  if (IMG) asm volatile("s_waitcnt vmcnt(6)" ::: "memory");
  else     asm volatile("s_waitcnt vmcnt(0) lgkmcnt(0)" ::: "memory");
  __builtin_amdgcn_sched_barrier(0);
  __builtin_amdgcn_s_barrier();

#pragma unroll 1
  for (int t = 0; t < 32; ++t) {
    short8 af[4], bf[2];
    // ---- half ks=0 ----
#pragma unroll
    for (int mt = 0; mt < 4; ++mt)
      af[mt] = *(const short8*)(p0 + (4*wr + mt)*2048 + lane*16);
#pragma unroll
    for (int g2 = 0; g2 < 2; ++g2)
      bf[g2] = *(const short8*)(p0 + 16384 + (sB*2 + g2)*1024 + lane*16);
    if (t < 30) stageA(p2, t + 2);
    __builtin_amdgcn_sched_barrier(0);        // keep glds issued before MFMA cluster
    __builtin_amdgcn_s_setprio(1);
#pragma unroll
    for (int mt = 0; mt < 4; ++mt)
#pragma unroll
      for (int g2 = 0; g2 < 2; ++g2)
        acc[mt][g2] = __builtin_amdgcn_mfma_f32_32x32x16_bf16(af[mt], bf[g2], acc[mt][g2], 0, 0, 0);
    __builtin_amdgcn_s_setprio(0);
    // ---- half ks=1 ----
#pragma unroll
    for (int mt = 0; mt < 4; ++mt)
      af[mt] = *(const short8*)(p0 + (4*wr + mt)*2048 + 1024 + lane*16);
#pragma unroll
    for (int g2 = 0; g2 < 2; ++g2)
      bf[g2] = *(const short8*)(p0 + 16384 + ((2 + sB)*2 + g2)*1024 + lane*16);
    if (t < 30) stageB(p2, t + 2);
    __builtin_amdgcn_sched_barrier(0);
    __builtin_amdgcn_s_setprio(1);
#pragma unroll
    for (int mt = 0; mt < 4; ++mt)
#pragma unroll
      for (int g2 = 0; g2 < 2; ++g2)
        acc[mt][g2] = __builtin_amdgcn_mfma_f32_32x32x16_bf16(af[mt], bf[g2], acc[mt][g2], 0, 0, 0);
    __builtin_amdgcn_s_setprio(0);
    // ---- kt boundary (sole barrier): drain stage(t+1), keep stage(t+2) in flight ----
    if (IMG) {
      if (t < 30) asm volatile("s_waitcnt vmcnt(6)" ::: "memory");
      else        asm volatile("s_waitcnt vmcnt(0)" ::: "memory");
    } else {
      asm volatile("s_waitcnt vmcnt(0) lgkmcnt(0)" ::: "memory");
    }
    __builtin_amdgcn_sched_barrier(0);
    __builtin_amdgcn_s_barrier();
    { char* tmp = p0; p0 = p1; p1 = p2; p2 = tmp; }
  }
  __syncthreads();

  // ---- epilogue: publish H to LDS ----
  char* H1r = lds;            // [vid(8)][col(64)][64B col-major rows, 16B-XOR swz] = 32K
  char* H0r = lds + 32768;    // [vid(8)][g2(2)][rh(2)][lane(64)][16B] C-layout bf16 = 32K
  if (sB == 1) {
#pragma unroll
    for (int mt = 0; mt < 4; ++mt) {
      int vid = 4*wr + mt;
#pragma unroll
      for (int g2 = 0; g2 < 2; ++g2) {
        int col = g2*32 + l31;
        int xw = (col & 3) << 4;
        char* cb = H1r + vid*4096 + col*64;
#pragma unroll
        for (int j = 0; j < 4; ++j) {
          ushort4v pk;
          pk.x = f2bf(acc[mt][g2][4*j+0]);
          pk.y = f2bf(acc[mt][g2][4*j+1]);
          pk.z = f2bf(acc[mt][g2][4*j+2]);
          pk.w = f2bf(acc[mt][g2][4*j+3]);
          *(ushort4v*)(cb + ((j*16 + lh*8) ^ xw)) = pk;
        }
      }
    }
  } else {
#pragma unroll
    for (int mt = 0; mt < 4; ++mt) {
      int vid = 4*wr + mt;
#pragma unroll
      for (int g2 = 0; g2 < 2; ++g2) {
        char* cb = H0r + (size_t)(vid*2 + g2)*2048 + lane*16;
        S8 lo, hi;
#pragma unroll
        for (int e = 0; e < 8; ++e) { lo.u[e] = f2bf(acc[mt][g2][e]); hi.u[e] = f2bf(acc[mt][g2][8+e]); }
        *(short8*)cb = lo.v;
        *(short8*)(cb + 1024) = hi.v;
      }
    }
  }
  __syncthreads();

  // ---- combine: wave w handles graphs 2w, 2w+1 ----
#pragma unroll 1
  for (int vg = 0; vg < 2; ++vg) {
    int v = wave*2 + vg;
    int v2 = idxp[v];
    f32x16 agg[2][2];
#pragma unroll
    for (int nt = 0; nt < 2; ++nt)
#pragma unroll
      for (int g2 = 0; g2 < 2; ++g2)
#pragma unroll
        for (int r = 0; r < 16; ++r) agg[nt][g2][r] = 0.f;

#pragma unroll
    for (int ks = 0; ks < 4; ++ks) {
      int vsel = (ks < 2) ? v : v2;
      int ksl = ks & 1;
      short8 aof0 = *(const short8*)((const char*)aofrag + (size_t)((0*4 + ks)*64 + lane)*16);
      short8 aof1 = *(const short8*)((const char*)aofrag + (size_t)((1*4 + ks)*64 + lane)*16);
#pragma unroll
      for (int g2 = 0; g2 < 2; ++g2) {
        int col = g2*32 + l31;
        int xw = (col & 3) << 4;
        short8 hf = *(const short8*)(H1r + vsel*4096 + col*64 + ((ksl*32 + lh*16) ^ xw));
        agg[0][g2] = __builtin_amdgcn_mfma_f32_32x32x16_bf16(aof0, hf, agg[0][g2], 0, 0, 0);
        agg[1][g2] = __builtin_amdgcn_mfma_f32_32x32x16_bf16(aof1, hf, agg[1][g2], 0, 0, 0);
      }
    }

    size_t gid = (size_t)b*8 + v;
    size_t obase = gid * 32768;
#pragma unroll
    for (int g2 = 0; g2 < 2; ++g2) {
      int g = g8*128 + gp*64 + g2*32 + l31;
      float sc = scale2[g], sh = shift2[g];
      S8 h0a0, h0a1, h0b0, h0b1;
      h0a0.v = *(const short8*)(H0r + (size_t)(v *2 + g2)*2048 + lane*16);
      h0a1.v = *(const short8*)(H0r + (size_t)(v *2 + g2)*2048 + 1024 + lane*16);
      h0b0.v = *(const short8*)(H0r + (size_t)(v2*2 + g2)*2048 + lane*16);
      h0b1.v = *(const short8*)(H0r + (size_t)(v2*2 + g2)*2048 + 1024 + lane*16);
#pragma unroll
      for (int j = 0; j < 4; ++j) {
        int i00 = j*8 + lh*4;
        float res[4];
#pragma unroll
        for (int jj = 0; jj < 4; ++jj) {
          int q = j*4 + jj;
          int i = i00 + jj;
          float h0v  = (q < 8) ? bf2f(h0a0.u[q]) : bf2f(h0a1.u[q-8]);
          float h0v2 = (q < 8) ? bf2f(h0b0.u[q]) : bf2f(h0b1.u[q-8]);
          float va = diagA[i]      * h0v  + agg[0][g2][q];
          float vb = diagA[32 + i] * h0v2 + agg[1][g2][q];
          va = fmaxf(va * sc + sh, 0.f);
          vb = fmaxf(vb * sc + sh, 0.f);
          res[jj] = 0.5f * (va + vb);
        }
        if (CH == 0) {
          float4 o4;
          o4.x = 0.5f*res[0]; o4.y = 0.5f*res[1]; o4.z = 0.5f*res[2]; o4.w = 0.5f*res[3];
          *(float4*)(out + obase + (size_t)g*32 + i00) = o4;
        } else if (CH == 1) {
#pragma unroll
          for (int jj = 0; jj < 4; ++jj)
            out[obase + (size_t)(i00 + jj)*1024 + g] += 0.25f * res[jj];
        } else {
#pragma unroll
          for (int jj = 0; jj < 4; ++jj)
            out[obase + (size_t)(g >> 5)*1024 + (size_t)(i00 + jj)*32 + (g & 31)] += 0.25f * res[jj];
        }
      }
    }
  }
}

extern "C" void kernel_launch(void* const* d_in, const int* in_sizes, int n_in,
                              void* d_out, int out_size, void* d_ws, size_t ws_size,
                              hipStream_t stream) {
  (void)in_sizes; (void)n_in; (void)out_size;
  const float* x    = (const float*)d_in[0];
  const int*   idx  = (const int*)d_in[1];
  const int*   adj1 = (const int*)d_in[2];
  const int*   adj2 = (const int*)d_in[3];
  const float *W[3], *e[3], *bb[3], *gm[3], *bt[3], *rm[3], *rv[3];
  for (int c = 0; c < 3; ++c) {
    int base = 4 + c*7;
    W[c]  = (const float*)d_in[base + 0];
    e[c]  = (const float*)d_in[base + 1];
    bb[c] = (const float*)d_in[base + 2];
    gm[c] = (const float*)d_in[base + 3];
    bt[c] = (const float*)d_in[base + 4];
    rm[c] = (const float*)d_in[base + 5];
    rv[c] = (const float*)d_in[base + 6];
  }
  char* ws = (char*)d_ws;
  unsigned short* wfrag  = (unsigned short*)ws;                    // 12 MB
  unsigned short* aofrag = (unsigned short*)(ws + 12582912);
  float* diagA  = (float*)(ws + 12607488);
  float* scale2 = (float*)(ws + 12608256);
  float* shift2 = (float*)(ws + 12620544);
  unsigned short* ximg = (unsigned short*)(ws + 16777216);         // up to 3 x 32 MB
  bool img3 = ws_size >= (size_t)(16777216 + 3*33554432);
  bool img1 = ws_size >= (size_t)(16777216 + 33554432);

  prep_w<<<3072, 256, 0, stream>>>(W[0], W[1], W[2], wfrag);
  prep_misc<<<3, 256, 0, stream>>>(
      e[0], adj1, bb[0], gm[0], bt[0], rm[0], rv[0],
      e[1], adj2, bb[1], gm[1], bt[1], rm[1], rv[1],
      e[2], adj2, bb[2], gm[2], bt[2], rm[2], rv[2],
      aofrag, diagA, scale2, shift2);

  float* out = (float*)d_out;
  if (img3) {
    prep_x_all<<<512, 256, 0, stream>>>(x, ximg);
    gconv<0,1><<<1024, 256, 0, stream>>>(x, idx, wfrag, ximg, aofrag,
                                         diagA, scale2, shift2, out);
    gconv<1,1><<<1024, 256, 0, stream>>>(x, idx, wfrag + 2097152, ximg + 16777216, aofrag + 4096,
                                         diagA + 64,  scale2 + 1024, shift2 + 1024, out);
    gconv<2,1><<<1024, 256, 0, stream>>>(x, idx, wfrag + 4194304, ximg + 33554432, aofrag + 8192,
                                         diagA + 128, scale2 + 2048, shift2 + 2048, out);
  } else if (img1) {
    prep_x2<<<8192, 256, 0, stream>>>(x, 0, ximg);
    gconv<0,1><<<1024, 256, 0, stream>>>(x, idx, wfrag, ximg, aofrag,
                                         diagA, scale2, shift2, out);
    prep_x2<<<8192, 256, 0, stream>>>(x, 1, ximg);
    gconv<1,1><<<1024, 256, 0, stream>>>(x, idx, wfrag + 2097152, ximg, aofrag + 4096,
                                         diagA + 64,  scale2 + 1024, shift2 + 1024, out);
    prep_x2<<<8192, 256, 0, stream>>>(x, 2, ximg);
    gconv<2,1><<<1024, 256, 0, stream>>>(x, idx, wfrag + 4194304, ximg, aofrag + 8192,
                                         diagA + 128, scale2 + 2048, shift2 + 2048, out);
  } else {
    gconv<0,0><<<1024, 256, 0, stream>>>(x, idx, wfrag, ximg, aofrag,
                                         diagA, scale2, shift2, out);
    gconv<1,0><<<1024, 256, 0, stream>>>(x, idx, wfrag + 2097152, ximg, aofrag + 4096,
                                         diagA + 64,  scale2 + 1024, shift2 + 1024, out);
    gconv<2,0><<<1024, 256, 0, stream>>>(x, idx, wfrag + 4194304, ximg, aofrag + 8192,
                                         diagA + 128, scale2 + 2048, shift2 + 2048, out);
  }
}

// Round 20
// 299.238 us; speedup vs baseline: 1.0198x; 1.0198x over previous
//
#include <hip/hip_runtime.h>
#include <stdint.h>

typedef __attribute__((ext_vector_type(8))) short short8;
typedef __attribute__((ext_vector_type(16))) float f32x16;
typedef __attribute__((ext_vector_type(4))) unsigned short ushort4v;

union S8 { short8 v; unsigned short u[8]; };

static __device__ __forceinline__ unsigned short f2bf(float f) {
  union { float f; unsigned u; } v; v.f = f;
  unsigned r = v.u + 0x7fffu + ((v.u >> 16) & 1u);
  return (unsigned short)(r >> 16);
}
static __device__ __forceinline__ float bf2f(unsigned short u) {
  union { unsigned u; float f; } v; v.u = ((unsigned)u) << 16;
  return v.f;
}

static __device__ __forceinline__ void glds16(const void* g, void* l) {
  __builtin_amdgcn_global_load_lds(
      (const __attribute__((address_space(1))) unsigned int*)g,
      (__attribute__((address_space(3))) unsigned int*)l, 16, 0, 0);
}

// ---------------- merged prep: W-images + x-images (3ch) + misc in ONE launch ----------------
// blocks 0..3071: prep_w ; 3072..3583: prep_x_all (vid = bid-3072) ; 3584..3586: prep_misc.
// All parts write disjoint ws regions and read only inputs -> no cross-block deps.
__global__ __launch_bounds__(256) void prep_all(
    const float* __restrict__ Wa, const float* __restrict__ Wb, const float* __restrict__ Wc,
    unsigned short* __restrict__ wfrag,
    const float* __restrict__ x, unsigned short* __restrict__ ximg,
    const float* e0, const int* a0, const float* b0, const float* g0, const float* be0, const float* rm0, const float* rv0,
    const float* e1, const int* a1, const float* b1, const float* g1, const float* be1, const float* rm1, const float* rv1,
    const float* e2, const int* a2, const float* b2, const float* g2, const float* be2, const float* rm2, const float* rv2,
    unsigned short* __restrict__ aofrag, float* __restrict__ diagA,
    float* __restrict__ scale2, float* __restrict__ shift2) {
  __shared__ char shm[66048];
  int bid = blockIdx.x;
  int tid = threadIdx.x;

  if (bid < 3072) {
    // ---- prep_w: W -> per-(g8,kt) 16KB B-fragment images ----
    int t    = bid * 256 + tid;
    int lane = t & 63;
    int tt   = (t >> 6) & 7;
    int ks   = (t >> 9) & 1;
    int kt   = (t >> 10) & 31;
    int g8   = (t >> 15) & 7;
    int c    = t >> 18;
    const float* W = (c == 0) ? Wa : (c == 1) ? Wb : Wc;
    int s  = tt >> 2, gt = tt & 3;
    int g  = g8*128 + gt*32 + (lane & 31);
    int k0 = kt*32 + ks*16 + ((lane >> 5) * 8);
    const float* src = W + (size_t)s * 1048576 + (size_t)k0 * 1024 + g;
    unsigned short* dst = wfrag + (size_t)t * 8;
#pragma unroll
    for (int e = 0; e < 8; ++e) dst[e] = f2bf(src[(size_t)e * 1024]);
  } else if (bid < 3584) {
    // ---- prep_x_all: one view -> all three channel frag-images ----
    unsigned short* sx = (unsigned short*)shm;   // 32 rows x 1032 (pad 8)
    int vid = bid - 3072;
    const float* src = x + (size_t)vid * 32768;
    for (int j = tid; j < 8192; j += 256) {
      float4 u = *(const float4*)(src + (size_t)j * 4);
      int i = j >> 8;
      int r = (j & 255) * 4;
      unsigned short* d = &sx[i*1032 + r];
      d[0] = f2bf(u.x); d[1] = f2bf(u.y); d[2] = f2bf(u.z); d[3] = f2bf(u.w);
    }
    __syncthreads();
    int lane = tid & 63;
    int ks   = (tid >> 6) & 1;
    int half = tid >> 7;
    int i0 = lane & 31;
    int kq = (lane >> 5) * 8;
#pragma unroll 1
    for (int kth = 0; kth < 16; ++kth) {
      int kt = half*16 + kth;
      int k0 = kt*32 + ks*16 + kq;
      int b = k0 >> 5, cz = k0 & 31;
      size_t t8 = ((((size_t)vid*32 + kt)*2 + ks)*64 + lane) * 8;
      {
        S8 pk;
#pragma unroll
        for (int e = 0; e < 8; ++e) pk.u[e] = sx[b*1032 + (cz + e)*32 + i0];
        *(short8*)(ximg + t8) = pk.v;
      }
      {
        short8 v = *(const short8*)&sx[i0*1032 + k0];
        *(short8*)(ximg + 16777216 + t8) = v;
      }
      {
        short8 v = *(const short8*)&sx[b*1032 + i0*32 + cz];
        *(short8*)(ximg + 33554432 + t8) = v;
      }
    }
  } else {
    // ---- prep_misc: softmax A, Aoff frags, diag, BN affine ----
    float (*A)[64] = (float(*)[64])shm;
    int c = bid - 3584;
    const float* ev = (c==0)?e0:(c==1)?e1:e2;
    const int*   ad = (c==0)?a0:(c==1)?a1:a2;
    const float* bb = (c==0)?b0:(c==1)?b1:b2;
    const float* gm = (c==0)?g0:(c==1)?g1:g2;
    const float* bt = (c==0)?be0:(c==1)?be1:be2;
    const float* rm = (c==0)?rm0:(c==1)?rm1:rm2;
    const float* rv = (c==0)?rv0:(c==1)?rv1:rv2;
    if (tid < 64) {
      int n = tid;
      float mx = -3.0e38f;
      for (int m = 0; m < 64; ++m) {
        float lg = (ad[n*64+m] > 0) ? ev[n*64+m] : -9.0e15f;
        A[n][m] = lg; mx = fmaxf(mx, lg);
      }
      float ssum = 0.f;
      for (int m = 0; m < 64; ++m) { float p = __expf(A[n][m] - mx); A[n][m] = p; ssum += p; }
      float inv = 1.f / ssum;
      for (int m = 0; m < 64; ++m) A[n][m] *= inv;
    }
    __syncthreads();
    if (tid < 64) diagA[c*64 + tid] = A[tid][tid];
    for (int idx = tid; idx < 4096; idx += 256) {
      int e  = idx & 7;
      int l  = (idx >> 3) & 63;
      int ks = (idx >> 9) & 3;
      int nt = idx >> 11;
      int n = nt*32 + (l & 31);
      int m = ks*16 + ((l >> 5) * 8) + e;
      float vv = (m == n) ? 0.f : A[n][m];
      aofrag[c*4096 + idx] = f2bf(vv);
    }
    for (int g = tid; g < 1024; g += 256) {
      float sc = gm[g] * rsqrtf(rv[g] + 1e-5f);
      scale2[c*1024 + g] = sc;
      shift2[c*1024 + g] = bt[g] + (bb[g] - rm[g]) * sc;
    }
  }
}

// ---------------- standalone prep kernels (fallback paths) ----------------
__global__ __launch_bounds__(256) void prep_w(const float* __restrict__ Wa,
                                              const float* __restrict__ Wb,
                                              const float* __restrict__ Wc,
                                              unsigned short* __restrict__ wfrag) {
  int t    = blockIdx.x * 256 + threadIdx.x;
  int lane = t & 63;
  int tt   = (t >> 6) & 7;
  int ks   = (t >> 9) & 1;
  int kt   = (t >> 10) & 31;
  int g8   = (t >> 15) & 7;
  int c    = t >> 18;
  const float* W = (c == 0) ? Wa : (c == 1) ? Wb : Wc;
  int s  = tt >> 2, gt = tt & 3;
  int g  = g8*128 + gt*32 + (lane & 31);
  int k0 = kt*32 + ks*16 + ((lane >> 5) * 8);
  const float* src = W + (size_t)s * 1048576 + (size_t)k0 * 1024 + g;
  unsigned short* dst = wfrag + (size_t)t * 8;
#pragma unroll
  for (int e = 0; e < 8; ++e) dst[e] = f2bf(src[(size_t)e * 1024]);
}

__global__ __launch_bounds__(256) void prep_x2(const float* __restrict__ x,
                                               int c, unsigned short* __restrict__ ximg) {
  int t = blockIdx.x * 256 + threadIdx.x;
  int lane = t & 63;
  int ks = (t >> 6) & 1;
  int kt = (t >> 7) & 31;
  int vid = t >> 12;
  const float* src = x + (size_t)vid * 32768;
  int i = lane & 31;
  int k0 = kt*32 + ks*16 + ((lane >> 5) * 8);
  S8 pk;
  if (c == 0) {
#pragma unroll
    for (int e = 0; e < 8; ++e) pk.u[e] = f2bf(src[(size_t)(k0 + e)*32 + i]);
  } else {
    const float* sp = (c == 1) ? (src + i*1024 + k0)
                               : (src + (k0 >> 5)*1024 + i*32 + (k0 & 31));
    float4 u0 = *(const float4*)sp, u1 = *(const float4*)(sp + 4);
    pk.u[0]=f2bf(u0.x); pk.u[1]=f2bf(u0.y); pk.u[2]=f2bf(u0.z); pk.u[3]=f2bf(u0.w);
    pk.u[4]=f2bf(u1.x); pk.u[5]=f2bf(u1.y); pk.u[6]=f2bf(u1.z); pk.u[7]=f2bf(u1.w);
  }
  *(short8*)(ximg + (size_t)t * 8) = pk.v;
}

__global__ __launch_bounds__(256) void prep_misc(
    const float* e0, const int* a0, const float* b0, const float* g0, const float* be0, const float* rm0, const float* rv0,
    const float* e1, const int* a1, const float* b1, const float* g1, const float* be1, const float* rm1, const float* rv1,
    const float* e2, const int* a2, const float* b2, const float* g2, const float* be2, const float* rm2, const float* rv2,
    unsigned short* __restrict__ aofrag, float* __restrict__ diagA,
    float* __restrict__ scale2, float* __restrict__ shift2) {
  __shared__ float A[64][64];
  int c = blockIdx.x;
  int tid = threadIdx.x;
  const float* ev = (c==0)?e0:(c==1)?e1:e2;
  const int*   ad = (c==0)?a0:(c==1)?a1:a2;
  const float* bb = (c==0)?b0:(c==1)?b1:b2;
  const float* gm = (c==0)?g0:(c==1)?g1:g2;
  const float* bt = (c==0)?be0:(c==1)?be1:be2;
  const float* rm = (c==0)?rm0:(c==1)?rm1:rm2;
  const float* rv = (c==0)?rv0:(c==1)?rv1:rv2;
  if (tid < 64) {
    int n = tid;
    float mx = -3.0e38f;
    for (int m = 0; m < 64; ++m) {
      float lg = (ad[n*64+m] > 0) ? ev[n*64+m] : -9.0e15f;
      A[n][m] = lg; mx = fmaxf(mx, lg);
    }
    float ssum = 0.f;
    for (int m = 0; m < 64; ++m) { float p = __expf(A[n][m] - mx); A[n][m] = p; ssum += p; }
    float inv = 1.f / ssum;
    for (int m = 0; m < 64; ++m) A[n][m] *= inv;
  }
  __syncthreads();
  if (tid < 64) diagA[c*64 + tid] = A[tid][tid];
  for (int idx = tid; idx < 4096; idx += 256) {
    int e  = idx & 7;
    int l  = (idx >> 3) & 63;
    int ks = (idx >> 9) & 3;
    int nt = idx >> 11;
    int n = nt*32 + (l & 31);
    int m = ks*16 + ((l >> 5) * 8) + e;
    float vv = (m == n) ? 0.f : A[n][m];
    aofrag[c*4096 + idx] = f2bf(vv);
  }
  for (int g = tid; g < 1024; g += 256) {
    float sc = gm[g] * rsqrtf(rv[g] + 1e-5f);
    scale2[c*1024 + g] = sc;
    shift2[c*1024 + g] = bt[g] + (bb[g] - rm[g]) * sc;
  }
}

// ---------------- fallback A loader (IMG=0 only): f32 direct gather ----------------
template<int CH>
__device__ __forceinline__ void loadAfb(float av[2][8], const float* __restrict__ sview,
                                        int d0, int lh, int kt) {
#pragma unroll
  for (int ks = 0; ks < 2; ++ks) {
    int kb = kt*32 + ks*16 + lh*8;
    if (CH == 0) {
#pragma unroll
      for (int e = 0; e < 8; ++e) av[ks][e] = sview[(size_t)(kb + e)*32 + d0];
    } else if (CH == 1) {
      const float* sp = sview + d0*1024 + kb;
      *(float4*)&av[ks][0] = *(const float4*)sp;
      *(float4*)&av[ks][4] = *(const float4*)(sp + 4);
    } else {
      const float* sp = sview + kt*1024 + d0*32 + ks*16 + lh*8;
      *(float4*)&av[ks][0] = *(const float4*)sp;
      *(float4*)&av[ks][4] = *(const float4*)(sp + 4);
    }
  }
}

// ---------------- main fused channel kernel (r17/r19-verified, unchanged) ----------------
template<int CH, int IMG>
__global__ __launch_bounds__(256, 2) void gconv(
    const float* __restrict__ x, const int* __restrict__ idxp,
    const unsigned short* __restrict__ wimg, const unsigned short* __restrict__ ximg,
    const unsigned short* __restrict__ aofrag,
    const float* __restrict__ diagA, const float* __restrict__ scale2,
    const float* __restrict__ shift2, float* __restrict__ out) {
  __shared__ alignas(128) char lds[73728];
  int tid = threadIdx.x, lane = tid & 63, wave = tid >> 6;
  int l31 = lane & 31, lh = lane >> 5;
  int wr = wave >> 1, sB = wave & 1;
  int bid = blockIdx.x;
  int g8 = bid & 7, gp = (bid >> 3) & 1, b = bid >> 4;

  const char* wimgG8 = (const char*)wimg + (size_t)g8 * 524288 + lane*16;
  const char* srcAw  = (const char*)ximg + ((size_t)b*8 + 2*wave) * 65536 + lane*16;
  const float* xw0 = x + ((size_t)b*8 + 2*wave) * 32768;       // IMG=0 only
  const float* xw1 = xw0 + 32768;                              // IMG=0 only

  f32x16 acc[4][2];
#pragma unroll
  for (int mt = 0; mt < 4; ++mt)
#pragma unroll
    for (int g2 = 0; g2 < 2; ++g2)
#pragma unroll
      for (int r = 0; r < 16; ++r) acc[mt][g2][r] = 0.f;

  char* p0 = lds; char* p1 = lds + 24576; char* p2 = lds + 49152;

  auto stageA = [&](char* dst, int t) {     // 4 glds: vids 2w,2w+1 x ks 0,1
    if (IMG) {
#pragma unroll
      for (int j = 0; j < 4; ++j) {
        const char* s = srcAw + (size_t)(j >> 1)*65536 + (size_t)t*2048 + (j & 1)*1024;
        glds16(s, dst + (2*wave + (j >> 1))*2048 + (j & 1)*1024);
      }
    } else {
#pragma unroll
      for (int j = 0; j < 2; ++j) {
        alignas(16) float av[2][8];
        loadAfb<CH>(av, j ? xw1 : xw0, l31, lh, t);
#pragma unroll
        for (int ks = 0; ks < 2; ++ks) {
          S8 pk;
#pragma unroll
          for (int e = 0; e < 8; ++e) pk.u[e] = f2bf(av[ks][e]);
          *(short8*)(dst + (2*wave + j)*2048 + ks*1024 + lane*16) = pk.v;
        }
      }
    }
  };
  auto stageB = [&](char* dst, int t) {     // 2 glds: (ks=w>>1, s=w&1, g2=jj)
#pragma unroll
    for (int jj = 0; jj < 2; ++jj) {
      const char* s = wimgG8 + (size_t)(((t*2 + (wave >> 1))*8) + (wave & 1)*4 + gp*2 + jj)*1024;
      glds16(s, dst + 16384 + (wave*2 + jj)*1024);
    }
  };

  // ---- prologue: stage t0, t1 ----
  stageA(p0, 0); stageB(p0, 0);
  stageA(p1, 1); stageB(p1, 1);
  if (IMG) asm volatile("s_waitcnt vmcnt(6)" ::: "memory");
  else     asm volatile("s_waitcnt vmcnt(0) lgkmcnt(0)" ::: "memory");
  __builtin_amdgcn_sched_barrier(0);
  __builtin_amdgcn_s_barrier();

#pragma unroll 1
  for (int t = 0; t < 32; ++t) {
    short8 af[4], bf[2];
    // ---- half ks=0 ----
#pragma unroll
    for (int mt = 0; mt < 4; ++mt)
      af[mt] = *(const short8*)(p0 + (4*wr + mt)*2048 + lane*16);
#pragma unroll
    for (int g2 = 0; g2 < 2; ++g2)
      bf[g2] = *(const short8*)(p0 + 16384 + (sB*2 + g2)*1024 + lane*16);
    if (t < 30) stageA(p2, t + 2);
    __builtin_amdgcn_sched_barrier(0);        // keep glds issued before MFMA cluster
    __builtin_amdgcn_s_setprio(1);
#pragma unroll
    for (int mt = 0; mt < 4; ++mt)
#pragma unroll
      for (int g2 = 0; g2 < 2; ++g2)
        acc[mt][g2] = __builtin_amdgcn_mfma_f32_32x32x16_bf16(af[mt], bf[g2], acc[mt][g2], 0, 0, 0);
    __builtin_amdgcn_s_setprio(0);
    // ---- half ks=1 ----
#pragma unroll
    for (int mt = 0; mt < 4; ++mt)
      af[mt] = *(const short8*)(p0 + (4*wr + mt)*2048 + 1024 + lane*16);
#pragma unroll
    for (int g2 = 0; g2 < 2; ++g2)
      bf[g2] = *(const short8*)(p0 + 16384 + ((2 + sB)*2 + g2)*1024 + lane*16);
    if (t < 30) stageB(p2, t + 2);
    __builtin_amdgcn_sched_barrier(0);
    __builtin_amdgcn_s_setprio(1);
#pragma unroll
    for (int mt = 0; mt < 4; ++mt)
#pragma unroll
      for (int g2 = 0; g2 < 2; ++g2)
        acc[mt][g2] = __builtin_amdgcn_mfma_f32_32x32x16_bf16(af[mt], bf[g2], acc[mt][g2], 0, 0, 0);
    __builtin_amdgcn_s_setprio(0);
    // ---- kt boundary (sole barrier): drain stage(t+1), keep stage(t+2) in flight ----
    if (IMG) {
      if (t < 30) asm volatile("s_waitcnt vmcnt(6)" ::: "memory");
      else        asm volatile("s_waitcnt vmcnt(0)" ::: "memory");
    } else {
      asm volatile("s_waitcnt vmcnt(0) lgkmcnt(0)" ::: "memory");
    }
    __builtin_amdgcn_sched_barrier(0);
    __builtin_amdgcn_s_barrier();
    { char* tmp = p0; p0 = p1; p1 = p2; p2 = tmp; }
  }
  __syncthreads();

  // ---- epilogue: publish H to LDS ----
  char* H1r = lds;            // [vid(8)][col(64)][64B col-major rows, 16B-XOR swz] = 32K
  char* H0r = lds + 32768;    // [vid(8)][g2(2)][rh(2)][lane(64)][16B] C-layout bf16 = 32K
  if (sB == 1) {
#pragma unroll
    for (int mt = 0; mt < 4; ++mt) {
      int vid = 4*wr + mt;
#pragma unroll
      for (int g2 = 0; g2 < 2; ++g2) {
        int col = g2*32 + l31;
        int xw = (col & 3) << 4;
        char* cb = H1r + vid*4096 + col*64;
#pragma unroll
        for (int j = 0; j < 4; ++j) {
          ushort4v pk;
          pk.x = f2bf(acc[mt][g2][4*j+0]);
          pk.y = f2bf(acc[mt][g2][4*j+1]);
          pk.z = f2bf(acc[mt][g2][4*j+2]);
          pk.w = f2bf(acc[mt][g2][4*j+3]);
          *(ushort4v*)(cb + ((j*16 + lh*8) ^ xw)) = pk;
        }
      }
    }
  } else {
#pragma unroll
    for (int mt = 0; mt < 4; ++mt) {
      int vid = 4*wr + mt;
#pragma unroll
      for (int g2 = 0; g2 < 2; ++g2) {
        char* cb = H0r + (size_t)(vid*2 + g2)*2048 + lane*16;
        S8 lo, hi;
#pragma unroll
        for (int e = 0; e < 8; ++e) { lo.u[e] = f2bf(acc[mt][g2][e]); hi.u[e] = f2bf(acc[mt][g2][8+e]); }
        *(short8*)cb = lo.v;
        *(short8*)(cb + 1024) = hi.v;
      }
    }
  }
  __syncthreads();

  // ---- combine: wave w handles graphs 2w, 2w+1 ----
#pragma unroll 1
  for (int vg = 0; vg < 2; ++vg) {
    int v = wave*2 + vg;
    int v2 = idxp[v];
    f32x16 agg[2][2];
#pragma unroll
    for (int nt = 0; nt < 2; ++nt)
#pragma unroll
      for (int g2 = 0; g2 < 2; ++g2)
#pragma unroll
        for (int r = 0; r < 16; ++r) agg[nt][g2][r] = 0.f;

#pragma unroll
    for (int ks = 0; ks < 4; ++ks) {
      int vsel = (ks < 2) ? v : v2;
      int ksl = ks & 1;
      short8 aof0 = *(const short8*)((const char*)aofrag + (size_t)((0*4 + ks)*64 + lane)*16);
      short8 aof1 = *(const short8*)((const char*)aofrag + (size_t)((1*4 + ks)*64 + lane)*16);
#pragma unroll
      for (int g2 = 0; g2 < 2; ++g2) {
        int col = g2*32 + l31;
        int xw = (col & 3) << 4;
        short8 hf = *(const short8*)(H1r + vsel*4096 + col*64 + ((ksl*32 + lh*16) ^ xw));
        agg[0][g2] = __builtin_amdgcn_mfma_f32_32x32x16_bf16(aof0, hf, agg[0][g2], 0, 0, 0);
        agg[1][g2] = __builtin_amdgcn_mfma_f32_32x32x16_bf16(aof1, hf, agg[1][g2], 0, 0, 0);
      }
    }

    size_t gid = (size_t)b*8 + v;
    size_t obase = gid * 32768;
#pragma unroll
    for (int g2 = 0; g2 < 2; ++g2) {
      int g = g8*128 + gp*64 + g2*32 + l31;
      float sc = scale2[g], sh = shift2[g];
      S8 h0a0, h0a1, h0b0, h0b1;
      h0a0.v = *(const short8*)(H0r + (size_t)(v *2 + g2)*2048 + lane*16);
      h0a1.v = *(const short8*)(H0r + (size_t)(v *2 + g2)*2048 + 1024 + lane*16);
      h0b0.v = *(const short8*)(H0r + (size_t)(v2*2 + g2)*2048 + lane*16);
      h0b1.v = *(const short8*)(H0r + (size_t)(v2*2 + g2)*2048 + 1024 + lane*16);
#pragma unroll
      for (int j = 0; j < 4; ++j) {
        int i00 = j*8 + lh*4;
        float res[4];
#pragma unroll
        for (int jj = 0; jj < 4; ++jj) {
          int q = j*4 + jj;
          int i = i00 + jj;
          float h0v  = (q < 8) ? bf2f(h0a0.u[q]) : bf2f(h0a1.u[q-8]);
          float h0v2 = (q < 8) ? bf2f(h0b0.u[q]) : bf2f(h0b1.u[q-8]);
          float va = diagA[i]      * h0v  + agg[0][g2][q];
          float vb = diagA[32 + i] * h0v2 + agg[1][g2][q];
          va = fmaxf(va * sc + sh, 0.f);
          vb = fmaxf(vb * sc + sh, 0.f);
          res[jj] = 0.5f * (va + vb);
        }
        if (CH == 0) {
          float4 o4;
          o4.x = 0.5f*res[0]; o4.y = 0.5f*res[1]; o4.z = 0.5f*res[2]; o4.w = 0.5f*res[3];
          *(float4*)(out + obase + (size_t)g*32 + i00) = o4;
        } else if (CH == 1) {
#pragma unroll
          for (int jj = 0; jj < 4; ++jj)
            out[obase + (size_t)(i00 + jj)*1024 + g] += 0.25f * res[jj];
        } else {
#pragma unroll
          for (int jj = 0; jj < 4; ++jj)
            out[obase + (size_t)(g >> 5)*1024 + (size_t)(i00 + jj)*32 + (g & 31)] += 0.25f * res[jj];
        }
      }
    }
  }
}

extern "C" void kernel_launch(void* const* d_in, const int* in_sizes, int n_in,
                              void* d_out, int out_size, void* d_ws, size_t ws_size,
                              hipStream_t stream) {
  (void)in_sizes; (void)n_in; (void)out_size;
  const float* x    = (const float*)d_in[0];
  const int*   idx  = (const int*)d_in[1];
  const int*   adj1 = (const int*)d_in[2];
  const int*   adj2 = (const int*)d_in[3];
  const float *W[3], *e[3], *bb[3], *gm[3], *bt[3], *rm[3], *rv[3];
  for (int c = 0; c < 3; ++c) {
    int base = 4 + c*7;
    W[c]  = (const float*)d_in[base + 0];
    e[c]  = (const float*)d_in[base + 1];
    bb[c] = (const float*)d_in[base + 2];
    gm[c] = (const float*)d_in[base + 3];
    bt[c] = (const float*)d_in[base + 4];
    rm[c] = (const float*)d_in[base + 5];
    rv[c] = (const float*)d_in[base + 6];
  }
  char* ws = (char*)d_ws;
  unsigned short* wfrag  = (unsigned short*)ws;                    // 12 MB
  unsigned short* aofrag = (unsigned short*)(ws + 12582912);
  float* diagA  = (float*)(ws + 12607488);
  float* scale2 = (float*)(ws + 12608256);
  float* shift2 = (float*)(ws + 12620544);
  unsigned short* ximg = (unsigned short*)(ws + 16777216);         // up to 3 x 32 MB
  bool img3 = ws_size >= (size_t)(16777216 + 3*33554432);
  bool img1 = ws_size >= (size_t)(16777216 + 33554432);

  float* out = (float*)d_out;
  if (img3) {
    prep_all<<<3587, 256, 0, stream>>>(
        W[0], W[1], W[2], wfrag, x, ximg,
        e[0], adj1, bb[0], gm[0], bt[0], rm[0], rv[0],
        e[1], adj2, bb[1], gm[1], bt[1], rm[1], rv[1],
        e[2], adj2, bb[2], gm[2], bt[2], rm[2], rv[2],
        aofrag, diagA, scale2, shift2);
    gconv<0,1><<<1024, 256, 0, stream>>>(x, idx, wfrag, ximg, aofrag,
                                         diagA, scale2, shift2, out);
    gconv<1,1><<<1024, 256, 0, stream>>>(x, idx, wfrag + 2097152, ximg + 16777216, aofrag + 4096,
                                         diagA + 64,  scale2 + 1024, shift2 + 1024, out);
    gconv<2,1><<<1024, 256, 0, stream>>>(x, idx, wfrag + 4194304, ximg + 33554432, aofrag + 8192,
                                         diagA + 128, scale2 + 2048, shift2 + 2048, out);
  } else if (img1) {
    prep_w<<<3072, 256, 0, stream>>>(W[0], W[1], W[2], wfrag);
    prep_misc<<<3, 256, 0, stream>>>(
        e[0], adj1, bb[0], gm[0], bt[0], rm[0], rv[0],
        e[1], adj2, bb[1], gm[1], bt[1], rm[1], rv[1],
        e[2], adj2, bb[2], gm[2], bt[2], rm[2], rv[2],
        aofrag, diagA, scale2, shift2);
    prep_x2<<<8192, 256, 0, stream>>>(x, 0, ximg);
    gconv<0,1><<<1024, 256, 0, stream>>>(x, idx, wfrag, ximg, aofrag,
                                         diagA, scale2, shift2, out);
    prep_x2<<<8192, 256, 0, stream>>>(x, 1, ximg);
    gconv<1,1><<<1024, 256, 0, stream>>>(x, idx, wfrag + 2097152, ximg, aofrag + 4096,
                                         diagA + 64,  scale2 + 1024, shift2 + 1024, out);
    prep_x2<<<8192, 256, 0, stream>>>(x, 2, ximg);
    gconv<2,1><<<1024, 256, 0, stream>>>(x, idx, wfrag + 4194304, ximg, aofrag + 8192,
                                         diagA + 128, scale2 + 2048, shift2 + 2048, out);
  } else {
    prep_w<<<3072, 256, 0, stream>>>(W[0], W[1], W[2], wfrag);
    prep_misc<<<3, 256, 0, stream>>>(
        e[0], adj1, bb[0], gm[0], bt[0], rm[0], rv[0],
        e[1], adj2, bb[1], gm[1], bt[1], rm[1], rv[1],
        e[2], adj2, bb[2], gm[2], bt[2], rm[2], rv[2],
        aofrag, diagA, scale2, shift2);
    gconv<0,0><<<1024, 256, 0, stream>>>(x, idx, wfrag, ximg, aofrag,
                                         diagA, scale2, shift2, out);
    gconv<1,0><<<1024, 256, 0, stream>>>(x, idx, wfrag + 2097152, ximg, aofrag + 4096,
                                         diagA + 64,  scale2 + 1024, shift2 + 1024, out);
    gconv<2,0><<<1024, 256, 0, stream>>>(x, idx, wfrag + 4194304, ximg, aofrag + 8192,
                                         diagA + 128, scale2 + 2048, shift2 + 2048, out);
  }
}